// Round 3
// baseline (201.336 us; speedup 1.0000x reference)
//
#include <hip/hip_runtime.h>
#include <stdint.h>

// Problem constants (fixed by the reference).
#define BB 4
#define NN 4096
#define MM 4096
#define CC 16
#define KMAX 128

// Output layout (flat float32, reference return order).
static constexpr int LOCSR_OFF = 0;                      // B*N*3
static constexpr int DATAR_OFF = BB * NN * 3;            // 49152
static constexpr int IDXS_OFF  = DATAR_OFF + BB * NN * CC; // 311296
static constexpr int NB_OFF    = IDXS_OFF + BB * NN;       // 327680

// radius as f32 (jnp weak-scalar cast), R^2 as double product cast to f32
static constexpr float RAD_F = 0.14f;
static constexpr float R2F   = (float)(0.14 * 0.14);

// ---------------- K1: per-batch bbox -> grid params ----------------
__global__ void k_bbox(const float* __restrict__ locs, float* __restrict__ gp) {
    int b = blockIdx.x;
    __shared__ float smn[3][256], smx[3][256];
    int t = threadIdx.x;
    float mn[3] = {1e30f, 1e30f, 1e30f}, mx[3] = {-1e30f, -1e30f, -1e30f};
    const float* base = locs + b * NN * 3;
    for (int i = t; i < NN; i += 256) {
        for (int d = 0; d < 3; ++d) {
            float v = base[i * 3 + d];
            mn[d] = fminf(mn[d], v);
            mx[d] = fmaxf(mx[d], v);
        }
    }
    for (int d = 0; d < 3; ++d) { smn[d][t] = mn[d]; smx[d][t] = mx[d]; }
    __syncthreads();
    for (int s = 128; s > 0; s >>= 1) {
        if (t < s) {
            for (int d = 0; d < 3; ++d) {
                smn[d][t] = fminf(smn[d][t], smn[d][t + s]);
                smx[d][t] = fmaxf(smx[d][t], smx[d][t + s]);
            }
        }
        __syncthreads();
    }
    if (t == 0) {
        float low2[3], gdf[3];
        int gdi[3];
        for (int d = 0; d < 3; ++d) {
            float lo = smn[d][0], up = smx[d][0];
            // grid_dims = ceil(clip((up-lo)/radius, 0, 96))
            float u = __fdiv_rn(__fsub_rn(up, lo), RAD_F);
            u = fminf(fmaxf(u, 0.0f), 96.0f);
            float g = ceilf(u);
            // lower = center - grid_dims*radius*0.5
            float center = __fmul_rn(__fadd_rn(lo, up), 0.5f);
            low2[d] = __fsub_rn(center, __fmul_rn(__fmul_rn(g, RAD_F), 0.5f));
            gdf[d] = g;
            gdi[d] = max((int)g, 1);
        }
        float* o = gp + b * 8;
        o[0] = low2[0]; o[1] = low2[1]; o[2] = low2[2];
        o[3] = gdf[0];  o[4] = gdf[1];  o[5] = gdf[2];
        ((int*)o)[6] = gdi[1] * gdi[2]; // stride0
        ((int*)o)[7] = gdi[2];          // stride1
    }
}

// ---------------- K2: per-particle flat cell id ----------------
__global__ void k_cellid(const float* __restrict__ locs, const float* __restrict__ gp,
                         int* __restrict__ cid) {
    int idx = blockIdx.x * 256 + threadIdx.x; // < B*N
    int b = idx >> 12;
    int i = idx & (NN - 1);
    const float* o = gp + b * 8;
    int s0 = ((const int*)o)[6], s1 = ((const int*)o)[7];
    int cc[3];
    for (int d = 0; d < 3; ++d) {
        float x = locs[(b * NN + i) * 3 + d];
        float c = floorf(__fdiv_rn(__fsub_rn(x, o[d]), RAD_F));
        c = fminf(fmaxf(c, 0.0f), __fsub_rn(o[3 + d], 1.0f));
        cc[d] = (int)c;
    }
    cid[b * NN + i] = cc[0] * s0 + cc[1] * s1 + cc[2];
}

// ---------------- K3: stable rank sort + scatter ----------------
__global__ void __launch_bounds__(64) k_rank(const float* __restrict__ locs,
                                             const float* __restrict__ data,
                                             const int* __restrict__ cid,
                                             float* __restrict__ out,
                                             float4* __restrict__ sp4) {
    __shared__ int4 keys4[NN / 4]; // 16 KB
    int blk = blockIdx.x;
    int b = blk >> 6;
    int lane = threadIdx.x;
    int i = (blk & 63) * 64 + lane;
    const int4* kg = (const int4*)(cid + b * NN);
    for (int k = lane; k < NN / 4; k += 64) keys4[k] = kg[k];
    __syncthreads();
    const int* keys = (const int*)keys4;
    int key = keys[i];
    int rank = 0;
    for (int j4 = 0; j4 < NN / 4; ++j4) {
        int4 kv = keys4[j4];
        int jb = j4 * 4;
        rank += (kv.x < key) || (kv.x == key && (jb    ) < i);
        rank += (kv.y < key) || (kv.y == key && (jb + 1) < i);
        rank += (kv.z < key) || (kv.z == key && (jb + 2) < i);
        rank += (kv.w < key) || (kv.w == key && (jb + 3) < i);
    }
    int src = b * NN + i, dst = b * NN + rank;
    float x = locs[src * 3 + 0], y = locs[src * 3 + 1], z = locs[src * 3 + 2];
    out[IDXS_OFF + dst] = (float)i;           // idxs[new] = old (as f32)
    out[LOCSR_OFF + dst * 3 + 0] = x;
    out[LOCSR_OFF + dst * 3 + 1] = y;
    out[LOCSR_OFF + dst * 3 + 2] = z;
    const float4* dsrc = (const float4*)(data + src * 16);
    float4* ddst = (float4*)(out + DATAR_OFF + dst * 16);
    ddst[0] = dsrc[0]; ddst[1] = dsrc[1]; ddst[2] = dsrc[2]; ddst[3] = dsrc[3];
    // pn = (x*x + y*y) + z*z, numpy pairwise-sum (forward) order
    float pn = __fadd_rn(__fadd_rn(__fmul_rn(x, x), __fmul_rn(y, y)), __fmul_rn(z, z));
    sp4[dst] = make_float4(x, y, z, pn);
}

// ---------------- K4: brute-force radius search, wave per query ----------------
// cross via GEMM-style FMA-forward k-loop (OpenBLAS/Eigen sgemm):
//   c = q0*x (rounded once); c = fma(q1,y,c); c = fma(q2,z,c)
__global__ void __launch_bounds__(1024) k_neighbors(const float* __restrict__ qlocs,
                                                    const float4* __restrict__ sp4,
                                                    float* __restrict__ out) {
    __shared__ float4 sp[NN]; // 64 KB
    int b = blockIdx.x >> 8;  // 256 blocks per batch
    int t = threadIdx.x;
    const float4* src = sp4 + b * NN;
    for (int k = t; k < NN; k += 1024) sp[k] = src[k];
    __syncthreads();
    int wave = t >> 6, lane = t & 63;
    int m = (blockIdx.x & 255) * 16 + wave;
    const float* q = qlocs + (b * MM + m) * 3;
    float q0 = q[0], q1 = q[1], q2 = q[2];
    float qn = __fadd_rn(__fadd_rn(__fmul_rn(q0, q0), __fmul_rn(q1, q1)), __fmul_rn(q2, q2));
    float* nb = out + NB_OFF + (b * MM + m) * KMAX;
    int count = 0;
    for (int c = 0; c < NN / 64; ++c) {
        int p = c * 64 + lane;
        float4 P = sp[p];
        float cross = fmaf(q2, P.z, fmaf(q1, P.y, __fmul_rn(q0, P.x)));
        float dist2 = __fsub_rn(__fadd_rn(qn, P.w), __fmul_rn(2.0f, cross));
        bool hit = dist2 <= R2F;
        unsigned long long bal = __ballot(hit);
        if (hit) {
            int pos = count + __popcll(bal & ((1ull << lane) - 1ull));
            if (pos < KMAX) nb[pos] = (float)p;
        }
        count += __popcll(bal);
        if (count >= KMAX) break; // wave-uniform
    }
    for (int j = count + lane; j < KMAX; j += 64) nb[j] = -1.0f;
}

extern "C" void kernel_launch(void* const* d_in, const int* in_sizes, int n_in,
                              void* d_out, int out_size, void* d_ws, size_t ws_size,
                              hipStream_t stream) {
    const float* locs  = (const float*)d_in[0];
    const float* data  = (const float*)d_in[1];
    const float* qlocs = (const float*)d_in[2];
    float* out = (float*)d_out;
    char* ws = (char*)d_ws;
    float*  gp  = (float*)ws;                                   // 4*8 floats
    int*    cid = (int*)(ws + 256);                              // B*N ints
    float4* sp4 = (float4*)(ws + 256 + BB * NN * sizeof(int));   // B*N float4

    k_bbox<<<BB, 256, 0, stream>>>(locs, gp);
    k_cellid<<<(BB * NN) / 256, 256, 0, stream>>>(locs, gp, cid);
    k_rank<<<BB * 64, 64, 0, stream>>>(locs, data, cid, out, sp4);
    k_neighbors<<<BB * 256, 1024, 0, stream>>>(qlocs, sp4, out);
}

// Round 4
// 106.240 us; speedup vs baseline: 1.8951x; 1.8951x over previous
//
#include <hip/hip_runtime.h>
#include <stdint.h>

// Problem constants (fixed by the reference).
#define BB 4
#define NN 4096
#define MM 4096
#define CC 16
#define KMAX 128

// Output layout (flat float32, reference return order).
static constexpr int LOCSR_OFF = 0;                      // B*N*3
static constexpr int DATAR_OFF = BB * NN * 3;            // 49152
static constexpr int IDXS_OFF  = DATAR_OFF + BB * NN * CC; // 311296
static constexpr int NB_OFF    = IDXS_OFF + BB * NN;       // 327680

// radius as f32 (jnp weak-scalar cast), R^2 as double product cast to f32
static constexpr float RAD_F = 0.14f;
static constexpr float R2F   = (float)(0.14 * 0.14);

// ---------------- K1: per-batch bbox -> grid params ----------------
__global__ void __launch_bounds__(1024) k_bbox(const float* __restrict__ locs,
                                               float* __restrict__ gp) {
    int b = blockIdx.x;
    __shared__ float smn[3][1024], smx[3][1024];
    int t = threadIdx.x;
    float mn[3] = {1e30f, 1e30f, 1e30f}, mx[3] = {-1e30f, -1e30f, -1e30f};
    const float* base = locs + b * NN * 3;
    for (int i = t; i < NN; i += 1024) {
        for (int d = 0; d < 3; ++d) {
            float v = base[i * 3 + d];
            mn[d] = fminf(mn[d], v);
            mx[d] = fmaxf(mx[d], v);
        }
    }
    for (int d = 0; d < 3; ++d) { smn[d][t] = mn[d]; smx[d][t] = mx[d]; }
    __syncthreads();
    for (int s = 512; s > 0; s >>= 1) {
        if (t < s) {
            for (int d = 0; d < 3; ++d) {
                smn[d][t] = fminf(smn[d][t], smn[d][t + s]);
                smx[d][t] = fmaxf(smx[d][t], smx[d][t + s]);
            }
        }
        __syncthreads();
    }
    if (t == 0) {
        float low2[3], gdf[3];
        int gdi[3];
        for (int d = 0; d < 3; ++d) {
            float lo = smn[d][0], up = smx[d][0];
            // grid_dims = ceil(clip((up-lo)/radius, 0, 96))
            float u = __fdiv_rn(__fsub_rn(up, lo), RAD_F);
            u = fminf(fmaxf(u, 0.0f), 96.0f);
            float g = ceilf(u);
            // lower = center - grid_dims*radius*0.5
            float center = __fmul_rn(__fadd_rn(lo, up), 0.5f);
            low2[d] = __fsub_rn(center, __fmul_rn(__fmul_rn(g, RAD_F), 0.5f));
            gdf[d] = g;
            gdi[d] = max((int)g, 1);
        }
        float* o = gp + b * 8;
        o[0] = low2[0]; o[1] = low2[1]; o[2] = low2[2];
        o[3] = gdf[0];  o[4] = gdf[1];  o[5] = gdf[2];
        ((int*)o)[6] = gdi[1] * gdi[2]; // stride0
        ((int*)o)[7] = gdi[2];          // stride1
    }
}

// ---------------- K2: per-particle flat cell id ----------------
__global__ void k_cellid(const float* __restrict__ locs, const float* __restrict__ gp,
                         int* __restrict__ cid) {
    int idx = blockIdx.x * 256 + threadIdx.x; // < B*N
    int b = idx >> 12;
    int i = idx & (NN - 1);
    const float* o = gp + b * 8;
    int s0 = ((const int*)o)[6], s1 = ((const int*)o)[7];
    int cc[3];
    for (int d = 0; d < 3; ++d) {
        float x = locs[(b * NN + i) * 3 + d];
        float c = floorf(__fdiv_rn(__fsub_rn(x, o[d]), RAD_F));
        c = fminf(fmaxf(c, 0.0f), __fsub_rn(o[3 + d], 1.0f));
        cc[d] = (int)c;
    }
    cid[b * NN + i] = cc[0] * s0 + cc[1] * s1 + cc[2];
}

// ---------------- K3: stable rank sort + scatter ----------------
// 256 blocks x 1024 threads (16 waves). Block owns 64 particles (lane l of
// every wave owns particle chunk*64+l). Wave w scans key-chunk w (256 keys,
// wave-uniform broadcast int4 LDS reads); partial ranks reduced via LDS.
// Epilogue spread: wave 0 -> locs/idxs/sp4, waves 1..4 -> data float4 copy.
__global__ void __launch_bounds__(1024) k_rank(const float* __restrict__ locs,
                                               const float* __restrict__ data,
                                               const int* __restrict__ cid,
                                               float* __restrict__ out,
                                               float4* __restrict__ sp4) {
    __shared__ int4 keys4[NN / 4];   // 16 KB
    __shared__ int partial[16][64];  // 4 KB
    __shared__ int s_dst[64];
    int blk = blockIdx.x;
    int b = blk >> 6;
    int t = threadIdx.x;
    int wave = t >> 6, lane = t & 63;
    const int4* kg = (const int4*)(cid + b * NN);
    keys4[t] = kg[t]; // 1024 threads x int4 = all 4096 keys
    __syncthreads();
    int i = (blk & 63) * 64 + lane;            // owned particle (same per lane across waves)
    int key = ((const int*)keys4)[i];
    int rank = 0;
    int j0 = wave * 64;
#pragma unroll 4
    for (int j4 = j0; j4 < j0 + 64; ++j4) {
        int4 kv = keys4[j4];
        int jb = j4 * 4;
        rank += (kv.x < key) || (kv.x == key && (jb    ) < i);
        rank += (kv.y < key) || (kv.y == key && (jb + 1) < i);
        rank += (kv.z < key) || (kv.z == key && (jb + 2) < i);
        rank += (kv.w < key) || (kv.w == key && (jb + 3) < i);
    }
    partial[wave][lane] = rank;
    __syncthreads();
    if (wave == 0) {
        int r = 0;
#pragma unroll
        for (int w = 0; w < 16; ++w) r += partial[w][lane];
        s_dst[lane] = r;
    }
    __syncthreads();
    if (wave == 0) {
        int src = b * NN + i;
        int dst = b * NN + s_dst[lane];
        float x = locs[src * 3 + 0], y = locs[src * 3 + 1], z = locs[src * 3 + 2];
        out[IDXS_OFF + dst] = (float)i;        // idxs[new] = old (as f32)
        out[LOCSR_OFF + dst * 3 + 0] = x;
        out[LOCSR_OFF + dst * 3 + 1] = y;
        out[LOCSR_OFF + dst * 3 + 2] = z;
        // pn = (x*x + y*y) + z*z, numpy pairwise-sum (forward) order
        float pn = __fadd_rn(__fadd_rn(__fmul_rn(x, x), __fmul_rn(y, y)), __fmul_rn(z, z));
        sp4[dst] = make_float4(x, y, z, pn);
    } else if (wave <= 4) {
        int p = lane;                           // particle chunk index
        int ii = (blk & 63) * 64 + p;
        int dst = b * NN + s_dst[p];
        int c = wave - 1;                       // float4 chunk of the 16 data floats
        const float4* dsrc = (const float4*)(data + (b * NN + ii) * 16);
        float4* ddst = (float4*)(out + DATAR_OFF + dst * 16);
        ddst[c] = dsrc[c];
    }
}

// ---------------- K4: brute-force radius search, wave per query ----------------
// cross via GEMM-style FMA-forward k-loop (matches reference einsum):
//   c = q0*x (rounded once); c = fma(q1,y,c); c = fma(q2,z,c)
__global__ void __launch_bounds__(1024) k_neighbors(const float* __restrict__ qlocs,
                                                    const float4* __restrict__ sp4,
                                                    float* __restrict__ out) {
    __shared__ float4 sp[NN]; // 64 KB
    int b = blockIdx.x >> 8;  // 256 blocks per batch
    int t = threadIdx.x;
    const float4* src = sp4 + b * NN;
    for (int k = t; k < NN; k += 1024) sp[k] = src[k];
    __syncthreads();
    int wave = t >> 6, lane = t & 63;
    int m = (blockIdx.x & 255) * 16 + wave;
    const float* q = qlocs + (b * MM + m) * 3;
    float q0 = q[0], q1 = q[1], q2 = q[2];
    float qn = __fadd_rn(__fadd_rn(__fmul_rn(q0, q0), __fmul_rn(q1, q1)), __fmul_rn(q2, q2));
    float* nb = out + NB_OFF + (b * MM + m) * KMAX;
    int count = 0;
    for (int c = 0; c < NN / 64; ++c) {
        int p = c * 64 + lane;
        float4 P = sp[p];
        float cross = fmaf(q2, P.z, fmaf(q1, P.y, __fmul_rn(q0, P.x)));
        float dist2 = __fsub_rn(__fadd_rn(qn, P.w), __fmul_rn(2.0f, cross));
        bool hit = dist2 <= R2F;
        unsigned long long bal = __ballot(hit);
        if (hit) {
            int pos = count + __popcll(bal & ((1ull << lane) - 1ull));
            if (pos < KMAX) nb[pos] = (float)p;
        }
        count += __popcll(bal);
        if (count >= KMAX) break; // wave-uniform
    }
    for (int j = count + lane; j < KMAX; j += 64) nb[j] = -1.0f;
}

extern "C" void kernel_launch(void* const* d_in, const int* in_sizes, int n_in,
                              void* d_out, int out_size, void* d_ws, size_t ws_size,
                              hipStream_t stream) {
    const float* locs  = (const float*)d_in[0];
    const float* data  = (const float*)d_in[1];
    const float* qlocs = (const float*)d_in[2];
    float* out = (float*)d_out;
    char* ws = (char*)d_ws;
    float*  gp  = (float*)ws;                                   // 4*8 floats
    int*    cid = (int*)(ws + 256);                              // B*N ints
    float4* sp4 = (float4*)(ws + 256 + BB * NN * sizeof(int));   // B*N float4

    k_bbox<<<BB, 1024, 0, stream>>>(locs, gp);
    k_cellid<<<(BB * NN) / 256, 256, 0, stream>>>(locs, gp, cid);
    k_rank<<<BB * 64, 1024, 0, stream>>>(locs, data, cid, out, sp4);
    k_neighbors<<<BB * 256, 1024, 0, stream>>>(qlocs, sp4, out);
}

// Round 5
// 100.085 us; speedup vs baseline: 2.0116x; 1.0615x over previous
//
#include <hip/hip_runtime.h>
#include <stdint.h>

// Problem constants (fixed by the reference).
#define BB 4
#define NN 4096
#define MM 4096
#define CC 16
#define KMAX 128

// Output layout (flat float32, reference return order).
static constexpr int LOCSR_OFF = 0;                        // B*N*3
static constexpr int DATAR_OFF = BB * NN * 3;              // 49152
static constexpr int IDXS_OFF  = DATAR_OFF + BB * NN * CC; // 311296
static constexpr int NB_OFF    = IDXS_OFF + BB * NN;       // 327680

// radius as f32 (jnp weak-scalar cast), R^2 as double product cast to f32
static constexpr float RAD_F = 0.14f;
static constexpr float R2F   = (float)(0.14 * 0.14);

// Hash-grid limits
static constexpr int MAXC    = 96 * 96 * 96;   // max cells per batch
static constexpr int CSTRIDE = MAXC + 8;       // cell_start stride per batch

// ---------------- K1: per-batch bbox -> grid params (12 floats/batch) ----------------
// slots: [0-2] lower, [3-5] grid_dims(f), [6] s0, [7] s1, [8] num_cells, [9-11] gdi
__global__ void __launch_bounds__(1024) k_bbox(const float* __restrict__ locs,
                                               float* __restrict__ gp) {
    int b = blockIdx.x;
    __shared__ float smn[3][1024], smx[3][1024];
    int t = threadIdx.x;
    float mn[3] = {1e30f, 1e30f, 1e30f}, mx[3] = {-1e30f, -1e30f, -1e30f};
    const float* base = locs + b * NN * 3;
    for (int i = t; i < NN; i += 1024) {
        for (int d = 0; d < 3; ++d) {
            float v = base[i * 3 + d];
            mn[d] = fminf(mn[d], v);
            mx[d] = fmaxf(mx[d], v);
        }
    }
    for (int d = 0; d < 3; ++d) { smn[d][t] = mn[d]; smx[d][t] = mx[d]; }
    __syncthreads();
    for (int s = 512; s > 0; s >>= 1) {
        if (t < s) {
            for (int d = 0; d < 3; ++d) {
                smn[d][t] = fminf(smn[d][t], smn[d][t + s]);
                smx[d][t] = fmaxf(smx[d][t], smx[d][t + s]);
            }
        }
        __syncthreads();
    }
    if (t == 0) {
        float low2[3], gdf[3];
        int gdi[3];
        for (int d = 0; d < 3; ++d) {
            float lo = smn[d][0], up = smx[d][0];
            float u = __fdiv_rn(__fsub_rn(up, lo), RAD_F);
            u = fminf(fmaxf(u, 0.0f), 96.0f);
            float g = ceilf(u);
            float center = __fmul_rn(__fadd_rn(lo, up), 0.5f);
            low2[d] = __fsub_rn(center, __fmul_rn(__fmul_rn(g, RAD_F), 0.5f));
            gdf[d] = g;
            gdi[d] = max((int)g, 1);
        }
        float* o = gp + b * 12;
        o[0] = low2[0]; o[1] = low2[1]; o[2] = low2[2];
        o[3] = gdf[0];  o[4] = gdf[1];  o[5] = gdf[2];
        ((int*)o)[6]  = gdi[1] * gdi[2];            // s0
        ((int*)o)[7]  = gdi[2];                     // s1
        ((int*)o)[8]  = gdi[0] * gdi[1] * gdi[2];   // num_cells
        ((int*)o)[9]  = gdi[0];
        ((int*)o)[10] = gdi[1];
        ((int*)o)[11] = gdi[2];
    }
}

// ---------------- K2: per-particle flat cell id ----------------
__global__ void k_cellid(const float* __restrict__ locs, const float* __restrict__ gp,
                         int* __restrict__ cid) {
    int idx = blockIdx.x * 256 + threadIdx.x; // < B*N
    int b = idx >> 12;
    int i = idx & (NN - 1);
    const float* o = gp + b * 12;
    int s0 = ((const int*)o)[6], s1 = ((const int*)o)[7];
    int cc[3];
    for (int d = 0; d < 3; ++d) {
        float x = locs[(b * NN + i) * 3 + d];
        float c = floorf(__fdiv_rn(__fsub_rn(x, o[d]), RAD_F));
        c = fminf(fmaxf(c, 0.0f), __fsub_rn(o[3 + d], 1.0f));
        cc[d] = (int)c;
    }
    cid[b * NN + i] = cc[0] * s0 + cc[1] * s1 + cc[2];
}

// ---------------- K3: stable rank sort + scatter ----------------
// 256 blocks x 1024 threads (16 waves). Wave w scans key-chunk w for the
// block's 64 owned particles; partial ranks reduced via LDS. Also emits the
// sorted cell-id array (cs_sorted) for the cell_start build.
__global__ void __launch_bounds__(1024) k_rank(const float* __restrict__ locs,
                                               const float* __restrict__ data,
                                               const int* __restrict__ cid,
                                               float* __restrict__ out,
                                               float4* __restrict__ sp4,
                                               int* __restrict__ cs_sorted) {
    __shared__ int4 keys4[NN / 4];   // 16 KB
    __shared__ int partial[16][64];  // 4 KB
    __shared__ int s_dst[64];
    int blk = blockIdx.x;
    int b = blk >> 6;
    int t = threadIdx.x;
    int wave = t >> 6, lane = t & 63;
    const int4* kg = (const int4*)(cid + b * NN);
    keys4[t] = kg[t]; // 1024 threads x int4 = all 4096 keys
    __syncthreads();
    int i = (blk & 63) * 64 + lane;
    int key = ((const int*)keys4)[i];
    int rank = 0;
    int j0 = wave * 64;
#pragma unroll 4
    for (int j4 = j0; j4 < j0 + 64; ++j4) {
        int4 kv = keys4[j4];
        int jb = j4 * 4;
        rank += (kv.x < key) || (kv.x == key && (jb    ) < i);
        rank += (kv.y < key) || (kv.y == key && (jb + 1) < i);
        rank += (kv.z < key) || (kv.z == key && (jb + 2) < i);
        rank += (kv.w < key) || (kv.w == key && (jb + 3) < i);
    }
    partial[wave][lane] = rank;
    __syncthreads();
    if (wave == 0) {
        int r = 0;
#pragma unroll
        for (int w = 0; w < 16; ++w) r += partial[w][lane];
        s_dst[lane] = r;
    }
    __syncthreads();
    if (wave == 0) {
        int src = b * NN + i;
        int dst = b * NN + s_dst[lane];
        float x = locs[src * 3 + 0], y = locs[src * 3 + 1], z = locs[src * 3 + 2];
        out[IDXS_OFF + dst] = (float)i;        // idxs[new] = old (as f32)
        out[LOCSR_OFF + dst * 3 + 0] = x;
        out[LOCSR_OFF + dst * 3 + 1] = y;
        out[LOCSR_OFF + dst * 3 + 2] = z;
        cs_sorted[dst] = key;
        // pn = (x*x + y*y) + z*z, numpy pairwise-sum (forward) order
        float pn = __fadd_rn(__fadd_rn(__fmul_rn(x, x), __fmul_rn(y, y)), __fmul_rn(z, z));
        sp4[dst] = make_float4(x, y, z, pn);
    } else if (wave <= 4) {
        int p = lane;
        int ii = (blk & 63) * 64 + p;
        int dst = b * NN + s_dst[p];
        int c = wave - 1;
        const float4* dsrc = (const float4*)(data + (b * NN + ii) * 16);
        float4* ddst = (float4*)(out + DATAR_OFF + dst * 16);
        ddst[c] = dsrc[c];
    }
}

// ---------------- K3b: cell_start via binary search over sorted cell ids ----------------
__global__ void __launch_bounds__(256) k_cellstart(const int* __restrict__ cs_sorted,
                                                   const float* __restrict__ gp,
                                                   int* __restrict__ cell_start) {
    int b = blockIdx.y;
    int nc = ((const int*)(gp + b * 12))[8];
    const int* cs = cs_sorted + b * NN;
    int* cst = cell_start + b * CSTRIDE;
    for (int c = blockIdx.x * 256 + threadIdx.x; c <= nc; c += gridDim.x * 256) {
        int lo = 0, hi = NN; // first index with cs[idx] >= c
        while (lo < hi) {
            int mid = (lo + hi) >> 1;
            if (cs[mid] < c) lo = mid + 1; else hi = mid;
        }
        cst[c] = lo;
    }
}

// ---------------- K4: grid-pruned radius search, wave per query ----------------
// Candidates = <=27-cell neighborhood as ascending z-runs -> hits appended in
// ascending sorted-index order (matches reference). dist2 math identical to
// the verified brute-force version (FMA-forward cross).
__device__ inline void axis_range(float qd, float lo, int gd, int* c0, int* c1) {
    const float DL = RAD_F + 1e-4f; // conservative margin >> all fp rounding
    float vlo = (qd - DL - lo) / RAD_F;
    float vhi = (qd + DL - lo) / RAD_F;
    int a = (int)floorf(vlo), b = (int)floorf(vhi);
    *c0 = min(max(a, 0), gd - 1);
    *c1 = min(max(b, 0), gd - 1);
}

__global__ void __launch_bounds__(256, 8) k_neighbors(const float* __restrict__ qlocs,
                                                      const float4* __restrict__ sp4,
                                                      const int* __restrict__ cell_start,
                                                      const float* __restrict__ gp,
                                                      float* __restrict__ out) {
    int blk = blockIdx.x;        // 4096 total: b = blk>>10, 4 queries/block
    int b = blk >> 10;
    int wave = threadIdx.x >> 6, lane = threadIdx.x & 63;
    int m = (blk & 1023) * 4 + wave;
    const float* o = gp + b * 12;
    const int* oi = (const int*)o;
    int s0 = oi[6], s1 = oi[7];
    int gd0 = oi[9], gd1 = oi[10], gd2 = oi[11];
    const float* q = qlocs + (b * MM + m) * 3;
    float q0 = q[0], q1 = q[1], q2 = q[2];
    float qn = __fadd_rn(__fadd_rn(__fmul_rn(q0, q0), __fmul_rn(q1, q1)), __fmul_rn(q2, q2));
    int cx0, cx1, cy0, cy1, cz0, cz1;
    axis_range(q0, o[0], gd0, &cx0, &cx1);
    axis_range(q1, o[1], gd1, &cy0, &cy1);
    axis_range(q2, o[2], gd2, &cz0, &cz1);
    const float4* sp = sp4 + b * NN;
    const int* cst = cell_start + b * CSTRIDE;
    float* nb = out + NB_OFF + (b * MM + m) * KMAX;
    int count = 0;
    for (int cx = cx0; cx <= cx1; ++cx) {
        for (int cy = cy0; cy <= cy1; ++cy) {
            int base = cx * s0 + cy * s1;
            int ps = cst[base + cz0];
            int pe = cst[base + cz1 + 1];
            for (int p0 = ps; p0 < pe; p0 += 64) {
                int p = p0 + lane;
                float4 P = sp[p]; // <=63 over-read stays inside ws, masked below
                float cross = fmaf(q2, P.z, fmaf(q1, P.y, __fmul_rn(q0, P.x)));
                float dist2 = __fsub_rn(__fadd_rn(qn, P.w), __fmul_rn(2.0f, cross));
                bool hit = (p < pe) && (dist2 <= R2F);
                unsigned long long bal = __ballot(hit);
                if (hit) {
                    int pos = count + __popcll(bal & ((1ull << lane) - 1ull));
                    if (pos < KMAX) nb[pos] = (float)p;
                }
                count += __popcll(bal);
                if (count >= KMAX) goto done; // wave-uniform
            }
        }
    }
done:
    for (int j = count + lane; j < KMAX; j += 64) nb[j] = -1.0f;
}

extern "C" void kernel_launch(void* const* d_in, const int* in_sizes, int n_in,
                              void* d_out, int out_size, void* d_ws, size_t ws_size,
                              hipStream_t stream) {
    const float* locs  = (const float*)d_in[0];
    const float* data  = (const float*)d_in[1];
    const float* qlocs = (const float*)d_in[2];
    float* out = (float*)d_out;
    char* ws = (char*)d_ws;
    // ws layout
    float* gp        = (float*)ws;                         // 4*12 floats (512 B reserved)
    int*   cid       = (int*)(ws + 512);                   // 64 KB
    int*   cs_sorted = (int*)(ws + 512 + 65536);           // 64 KB
    float4* sp4      = (float4*)(ws + 512 + 2 * 65536);    // 256 KB
    int*   cell_start = (int*)(ws + 512 + 2 * 65536 + BB * NN * sizeof(float4)); // ~14 MB

    k_bbox<<<BB, 1024, 0, stream>>>(locs, gp);
    k_cellid<<<(BB * NN) / 256, 256, 0, stream>>>(locs, gp, cid);
    k_rank<<<BB * 64, 1024, 0, stream>>>(locs, data, cid, out, sp4, cs_sorted);
    k_cellstart<<<dim3(32, BB), 256, 0, stream>>>(cs_sorted, gp, cell_start);
    k_neighbors<<<BB * 1024, 256, 0, stream>>>(qlocs, sp4, cell_start, gp, out);
}

// Round 6
// 93.875 us; speedup vs baseline: 2.1447x; 1.0661x over previous
//
#include <hip/hip_runtime.h>
#include <stdint.h>

// Problem constants (fixed by the reference).
#define BB 4
#define NN 4096
#define MM 4096
#define CC 16
#define KMAX 128

// Output layout (flat float32, reference return order).
static constexpr int LOCSR_OFF = 0;                        // B*N*3
static constexpr int DATAR_OFF = BB * NN * 3;              // 49152
static constexpr int IDXS_OFF  = DATAR_OFF + BB * NN * CC; // 311296
static constexpr int NB_OFF    = IDXS_OFF + BB * NN;       // 327680

// radius as f32 (jnp weak-scalar cast), R^2 as double product cast to f32
static constexpr float RAD_F = 0.14f;
static constexpr float R2F   = (float)(0.14 * 0.14);

// Hash-grid limits
static constexpr int MAXC    = 96 * 96 * 96;   // max cells per batch
static constexpr int CSTRIDE = MAXC + 8;       // cell_start stride per batch

// ---------------- K1: per-batch bbox -> grid params + combined cell keys ----------------
// gp slots: [0-2] lower, [3-5] grid_dims(f), [6] s0, [7] s1, [8] num_cells, [9-11] gdi
// cid[b*NN+i] = cell_id*4096 + i  (u32 combined stable-sort key; max 3.62e9 < 2^32)
__global__ void __launch_bounds__(1024) k_grid(const float* __restrict__ locs,
                                               float* __restrict__ gp,
                                               unsigned* __restrict__ cid) {
    int b = blockIdx.x;
    __shared__ float smn[3][1024], smx[3][1024];
    __shared__ float sp_low[3], sp_gdf[3];
    __shared__ int sp_s0, sp_s1;
    int t = threadIdx.x;
    float mn[3] = {1e30f, 1e30f, 1e30f}, mx[3] = {-1e30f, -1e30f, -1e30f};
    const float* base = locs + b * NN * 3;
    for (int i = t; i < NN; i += 1024) {
        for (int d = 0; d < 3; ++d) {
            float v = base[i * 3 + d];
            mn[d] = fminf(mn[d], v);
            mx[d] = fmaxf(mx[d], v);
        }
    }
    for (int d = 0; d < 3; ++d) { smn[d][t] = mn[d]; smx[d][t] = mx[d]; }
    __syncthreads();
    for (int s = 512; s > 0; s >>= 1) {
        if (t < s) {
            for (int d = 0; d < 3; ++d) {
                smn[d][t] = fminf(smn[d][t], smn[d][t + s]);
                smx[d][t] = fmaxf(smx[d][t], smx[d][t + s]);
            }
        }
        __syncthreads();
    }
    if (t == 0) {
        float low2[3], gdf[3];
        int gdi[3];
        for (int d = 0; d < 3; ++d) {
            float lo = smn[d][0], up = smx[d][0];
            float u = __fdiv_rn(__fsub_rn(up, lo), RAD_F);
            u = fminf(fmaxf(u, 0.0f), 96.0f);
            float g = ceilf(u);
            float center = __fmul_rn(__fadd_rn(lo, up), 0.5f);
            low2[d] = __fsub_rn(center, __fmul_rn(__fmul_rn(g, RAD_F), 0.5f));
            gdf[d] = g;
            gdi[d] = max((int)g, 1);
        }
        float* o = gp + b * 12;
        o[0] = low2[0]; o[1] = low2[1]; o[2] = low2[2];
        o[3] = gdf[0];  o[4] = gdf[1];  o[5] = gdf[2];
        ((int*)o)[6]  = gdi[1] * gdi[2];            // s0
        ((int*)o)[7]  = gdi[2];                     // s1
        ((int*)o)[8]  = gdi[0] * gdi[1] * gdi[2];   // num_cells
        ((int*)o)[9]  = gdi[0];
        ((int*)o)[10] = gdi[1];
        ((int*)o)[11] = gdi[2];
        for (int d = 0; d < 3; ++d) { sp_low[d] = low2[d]; sp_gdf[d] = gdf[d]; }
        sp_s0 = gdi[1] * gdi[2];
        sp_s1 = gdi[2];
    }
    __syncthreads();
    float l0 = sp_low[0], l1 = sp_low[1], l2 = sp_low[2];
    float g0 = sp_gdf[0], g1 = sp_gdf[1], g2 = sp_gdf[2];
    int s0 = sp_s0, s1 = sp_s1;
    for (int i = t; i < NN; i += 1024) {
        float x0 = base[i * 3 + 0], x1 = base[i * 3 + 1], x2 = base[i * 3 + 2];
        float c0 = fminf(fmaxf(floorf(__fdiv_rn(__fsub_rn(x0, l0), RAD_F)), 0.0f), __fsub_rn(g0, 1.0f));
        float c1 = fminf(fmaxf(floorf(__fdiv_rn(__fsub_rn(x1, l1), RAD_F)), 0.0f), __fsub_rn(g1, 1.0f));
        float c2 = fminf(fmaxf(floorf(__fdiv_rn(__fsub_rn(x2, l2), RAD_F)), 0.0f), __fsub_rn(g2, 1.0f));
        unsigned cell = (unsigned)((int)c0 * s0 + (int)c1 * s1 + (int)c2);
        cid[b * NN + i] = cell * 4096u + (unsigned)i;
    }
}

// ---------------- K3: stable rank sort + scatter ----------------
// 256 blocks x 1024 threads (16 waves). Rank via single u32 compare on the
// combined key (stable by construction). Wave w scans key-chunk w; partial
// ranks reduced via LDS. Epilogue: wave0 locs/idxs/sp4/cs, waves1-4 data.
__global__ void __launch_bounds__(1024) k_rank(const float* __restrict__ locs,
                                               const float* __restrict__ data,
                                               const unsigned* __restrict__ cid,
                                               float* __restrict__ out,
                                               float4* __restrict__ sp4,
                                               unsigned* __restrict__ cs_sorted) {
    __shared__ uint4 keys4[NN / 4];  // 16 KB
    __shared__ int partial[16][64];  // 4 KB
    __shared__ int s_dst[64];
    int blk = blockIdx.x;
    int b = blk >> 6;
    int t = threadIdx.x;
    int wave = t >> 6, lane = t & 63;
    const uint4* kg = (const uint4*)(cid + b * NN);
    keys4[t] = kg[t]; // 1024 threads x uint4 = all 4096 keys
    __syncthreads();
    int i = (blk & 63) * 64 + lane;
    unsigned key = ((const unsigned*)keys4)[i];
    int rank = 0;
    int j0 = wave * 64;
#pragma unroll 8
    for (int j4 = j0; j4 < j0 + 64; ++j4) {
        uint4 kv = keys4[j4];
        rank += (kv.x < key) + (kv.y < key) + (kv.z < key) + (kv.w < key);
    }
    partial[wave][lane] = rank;
    __syncthreads();
    if (wave == 0) {
        int r = 0;
#pragma unroll
        for (int w = 0; w < 16; ++w) r += partial[w][lane];
        s_dst[lane] = r;
    }
    __syncthreads();
    if (wave == 0) {
        int src = b * NN + i;
        int dst = b * NN + s_dst[lane];
        float x = locs[src * 3 + 0], y = locs[src * 3 + 1], z = locs[src * 3 + 2];
        out[IDXS_OFF + dst] = (float)i;        // idxs[new] = old (as f32)
        out[LOCSR_OFF + dst * 3 + 0] = x;
        out[LOCSR_OFF + dst * 3 + 1] = y;
        out[LOCSR_OFF + dst * 3 + 2] = z;
        cs_sorted[dst] = key;                  // combined key; cell = key>>12
        // pn = (x*x + y*y) + z*z, numpy pairwise-sum (forward) order
        float pn = __fadd_rn(__fadd_rn(__fmul_rn(x, x), __fmul_rn(y, y)), __fmul_rn(z, z));
        sp4[dst] = make_float4(x, y, z, pn);
    } else if (wave <= 4) {
        int p = lane;
        int ii = (blk & 63) * 64 + p;
        int dst = b * NN + s_dst[p];
        int c = wave - 1;
        const float4* dsrc = (const float4*)(data + (b * NN + ii) * 16);
        float4* ddst = (float4*)(out + DATAR_OFF + dst * 16);
        ddst[c] = dsrc[c];
    }
}

// ---------------- K3b: cell_start via binary search over sorted combined keys ----------------
__global__ void __launch_bounds__(256) k_cellstart(const unsigned* __restrict__ cs_sorted,
                                                   const float* __restrict__ gp,
                                                   int* __restrict__ cell_start) {
    int b = blockIdx.y;
    int nc = ((const int*)(gp + b * 12))[8];
    const unsigned* cs = cs_sorted + b * NN;
    int* cst = cell_start + b * CSTRIDE;
    for (int c = blockIdx.x * 256 + threadIdx.x; c <= nc; c += gridDim.x * 256) {
        int lo = 0, hi = NN; // first index with cell(cs[idx]) >= c
        while (lo < hi) {
            int mid = (lo + hi) >> 1;
            if ((int)(cs[mid] >> 12) < c) lo = mid + 1; else hi = mid;
        }
        cst[c] = lo;
    }
}

// ---------------- K4: grid-pruned radius search, wave per query ----------------
// Candidates = <=27-cell neighborhood as ascending z-runs -> hits appended in
// ascending sorted-index order (matches reference). dist2 math identical to
// the verified brute-force version (FMA-forward cross).
__device__ inline void axis_range(float qd, float lo, int gd, int* c0, int* c1) {
    const float DL = RAD_F + 1e-4f; // conservative margin >> all fp rounding
    float vlo = (qd - DL - lo) / RAD_F;
    float vhi = (qd + DL - lo) / RAD_F;
    int a = (int)floorf(vlo), b = (int)floorf(vhi);
    *c0 = min(max(a, 0), gd - 1);
    *c1 = min(max(b, 0), gd - 1);
}

__global__ void __launch_bounds__(256, 8) k_neighbors(const float* __restrict__ qlocs,
                                                      const float4* __restrict__ sp4,
                                                      const int* __restrict__ cell_start,
                                                      const float* __restrict__ gp,
                                                      float* __restrict__ out) {
    int blk = blockIdx.x;        // 4096 total: b = blk>>10, 4 queries/block
    int b = blk >> 10;
    int wave = threadIdx.x >> 6, lane = threadIdx.x & 63;
    int m = (blk & 1023) * 4 + wave;
    const float* o = gp + b * 12;
    const int* oi = (const int*)o;
    int s0 = oi[6], s1 = oi[7];
    int gd0 = oi[9], gd1 = oi[10], gd2 = oi[11];
    const float* q = qlocs + (b * MM + m) * 3;
    float q0 = q[0], q1 = q[1], q2 = q[2];
    float qn = __fadd_rn(__fadd_rn(__fmul_rn(q0, q0), __fmul_rn(q1, q1)), __fmul_rn(q2, q2));
    int cx0, cx1, cy0, cy1, cz0, cz1;
    axis_range(q0, o[0], gd0, &cx0, &cx1);
    axis_range(q1, o[1], gd1, &cy0, &cy1);
    axis_range(q2, o[2], gd2, &cz0, &cz1);
    const float4* sp = sp4 + b * NN;
    const int* cst = cell_start + b * CSTRIDE;
    float* nb = out + NB_OFF + (b * MM + m) * KMAX;
    int count = 0;
    for (int cx = cx0; cx <= cx1; ++cx) {
        for (int cy = cy0; cy <= cy1; ++cy) {
            int base = cx * s0 + cy * s1;
            int ps = cst[base + cz0];
            int pe = cst[base + cz1 + 1];
            for (int p0 = ps; p0 < pe; p0 += 64) {
                int p = p0 + lane;
                float4 P = sp[p]; // <=63 over-read stays inside ws, masked below
                float cross = fmaf(q2, P.z, fmaf(q1, P.y, __fmul_rn(q0, P.x)));
                float dist2 = __fsub_rn(__fadd_rn(qn, P.w), __fmul_rn(2.0f, cross));
                bool hit = (p < pe) && (dist2 <= R2F);
                unsigned long long bal = __ballot(hit);
                if (hit) {
                    int pos = count + __popcll(bal & ((1ull << lane) - 1ull));
                    if (pos < KMAX) nb[pos] = (float)p;
                }
                count += __popcll(bal);
                if (count >= KMAX) goto done; // wave-uniform
            }
        }
    }
done:
    for (int j = count + lane; j < KMAX; j += 64) nb[j] = -1.0f;
}

extern "C" void kernel_launch(void* const* d_in, const int* in_sizes, int n_in,
                              void* d_out, int out_size, void* d_ws, size_t ws_size,
                              hipStream_t stream) {
    const float* locs  = (const float*)d_in[0];
    const float* data  = (const float*)d_in[1];
    const float* qlocs = (const float*)d_in[2];
    float* out = (float*)d_out;
    char* ws = (char*)d_ws;
    // ws layout
    float*    gp        = (float*)ws;                         // 4*12 floats (512 B reserved)
    unsigned* cid       = (unsigned*)(ws + 512);              // 64 KB
    unsigned* cs_sorted = (unsigned*)(ws + 512 + 65536);      // 64 KB
    float4*   sp4       = (float4*)(ws + 512 + 2 * 65536);    // 256 KB
    int* cell_start = (int*)(ws + 512 + 2 * 65536 + BB * NN * sizeof(float4)); // ~14 MB

    k_grid<<<BB, 1024, 0, stream>>>(locs, gp, cid);
    k_rank<<<BB * 64, 1024, 0, stream>>>(locs, data, cid, out, sp4, cs_sorted);
    k_cellstart<<<dim3(32, BB), 256, 0, stream>>>(cs_sorted, gp, cell_start);
    k_neighbors<<<BB * 1024, 256, 0, stream>>>(qlocs, sp4, cell_start, gp, out);
}